// Round 3
// baseline (26916.916 us; speedup 1.0000x reference)
//
#include <hip/hip_runtime.h>
#include <hip/hip_bf16.h>

#define BB 64
#define SS 1024
#define II 128
#define HH 256
#define OO 128

// Persistent recurrent kernel: one block per batch element. All f32.
// threads 0..255   -> rec rows   (W_rec)
// threads 256..511 -> cg rows    (W_cg)
// threads 512..767 -> eg rows    (W_eg)
// threads 768..1023-> inp rows   (W_in over x_t)
__global__ __launch_bounds__(1024)
void ltc_recurrent(const float* __restrict__ x,      // [B,S,I]
                   const float* __restrict__ W_in,   // [H,I]
                   const float* __restrict__ b_in,   // [H]
                   const float* __restrict__ W_rec,  // [H,H]
                   const float* __restrict__ b_rec,  // [H]
                   const float* __restrict__ W_cg,   // [H,H]
                   const float* __restrict__ b_cg,   // [H]
                   const float* __restrict__ W_eg,   // [H,H]
                   const float* __restrict__ b_eg,   // [H]
                   const float* __restrict__ tau,    // [H]
                   float* __restrict__ states)       // [B,S,H] f32 (output chunk 2)
{
    const int b = blockIdx.x;
    const int t = threadIdx.x;
    const int g = t >> 8;      // 0=rec, 1=cg, 2=eg, 3=inp
    const int r = t & 255;

    __shared__ __align__(16) float h_s[HH];
    __shared__ __align__(16) float x_s[II];
    __shared__ __align__(16) float accs[4][HH];

    const float4* wrow;
    float bias;
    if (g == 0)      { wrow = (const float4*)(W_rec + r * HH); bias = b_rec[r]; }
    else if (g == 1) { wrow = (const float4*)(W_cg  + r * HH); bias = b_cg[r];  }
    else if (g == 2) { wrow = (const float4*)(W_eg  + r * HH); bias = b_eg[r];  }
    else             { wrow = (const float4*)(W_in  + r * II); bias = b_in[r];  }

    float tau_inv = 0.f;
    if (t < HH) {
        tau_inv = 1.0f / tau[t];
        h_s[t] = 0.0f;   // h0 = 0; visibility covered by first in-loop barrier
    }

    const float* xb = x + (size_t)b * SS * II;
    float* st = states + (size_t)b * SS * HH;

    for (int step = 0; step < SS; ++step) {
        if (t < II) x_s[t] = xb[(size_t)step * II + t];
        __syncthreads();  // x_t ready; h from previous step visible

        float acc0 = bias, acc1 = 0.f;
        if (g < 3) {
            const float4* h4 = (const float4*)h_s;
#pragma unroll 8
            for (int kk = 0; kk < HH / 4; ++kk) {          // 64 x float4
                float4 w = wrow[kk];
                float4 hv = h4[kk];
                acc0 = fmaf(w.x, hv.x, acc0);
                acc1 = fmaf(w.y, hv.y, acc1);
                acc0 = fmaf(w.z, hv.z, acc0);
                acc1 = fmaf(w.w, hv.w, acc1);
            }
        } else {
            const float4* x4 = (const float4*)x_s;
#pragma unroll 8
            for (int kk = 0; kk < II / 4; ++kk) {          // 32 x float4
                float4 w = wrow[kk];
                float4 xv = x4[kk];
                acc0 = fmaf(w.x, xv.x, acc0);
                acc1 = fmaf(w.y, xv.y, acc1);
                acc0 = fmaf(w.z, xv.z, acc0);
                acc1 = fmaf(w.w, xv.w, acc1);
            }
        }
        accs[g][r] = acc0 + acc1;
        __syncthreads();  // all pre-activations ready

        if (t < HH) {
            float h   = h_s[t];
            float rec = accs[0][t];
            float cgp = accs[1][t];
            float egp = accs[2][t];
            float inp = accs[3][t];
            float cm  = 1.0f / (1.0f + expf(-cgp));
            float em  = tanhf(egp);
            float pre = inp + rec;
            float rl  = pre > 0.0f ? pre : 0.0f;
            float dh  = (rl - h) * tau_inv;   // (-h + relu)/tau
            dh = dh * cm + 0.1f * em;
            float hn = fmaf(0.1f, dh, h);     // h + DT*dhdt
            h_s[t] = hn;
            st[(size_t)step * HH + t] = hn;
        }
        // next iteration's first barrier orders h_s/accs reuse
    }
}

// Deferred output projection: outputs[row,o] = b_out[o] + sum_k states[row,k]*W_out[o,k]
// One block = 2 rows x 128 outputs. All f32.
__global__ __launch_bounds__(256)
void ltc_out(const float* __restrict__ states,  // [B*S, H]
             const float* __restrict__ W_out,   // [O,H]
             const float* __restrict__ b_out,   // [O]
             float* __restrict__ outputs)       // [B*S, O]
{
    const int t = threadIdx.x;
    const int o = t & (OO - 1);
    const size_t row = (size_t)blockIdx.x * 2 + (t >> 7);
    const float4* srow = (const float4*)(states + row * HH);
    const float4* wrow = (const float4*)(W_out + (size_t)o * HH);
    float acc0 = b_out[o], acc1 = 0.f;
#pragma unroll 8
    for (int kk = 0; kk < HH / 4; ++kk) {
        float4 w = wrow[kk];
        float4 s = srow[kk];
        acc0 = fmaf(w.x, s.x, acc0);
        acc1 = fmaf(w.y, s.y, acc1);
        acc0 = fmaf(w.z, s.z, acc0);
        acc1 = fmaf(w.w, s.w, acc1);
    }
    outputs[row * OO + o] = acc0 + acc1;
}

extern "C" void kernel_launch(void* const* d_in, const int* in_sizes, int n_in,
                              void* d_out, int out_size, void* d_ws, size_t ws_size,
                              hipStream_t stream) {
    const float* x      = (const float*)d_in[0];
    const float* W_in   = (const float*)d_in[1];
    const float* b_in   = (const float*)d_in[2];
    const float* W_rec  = (const float*)d_in[3];
    const float* b_rec  = (const float*)d_in[4];
    const float* W_out  = (const float*)d_in[5];
    const float* b_out  = (const float*)d_in[6];
    const float* W_cg   = (const float*)d_in[7];
    const float* b_cg   = (const float*)d_in[8];
    const float* W_eg   = (const float*)d_in[9];
    const float* b_eg   = (const float*)d_in[10];
    const float* tau    = (const float*)d_in[11];

    float* outputs = (float*)d_out;                       // [B,S,O]
    float* states  = outputs + (size_t)BB * SS * OO;      // [B,S,H]

    hipLaunchKernelGGL(ltc_recurrent, dim3(BB), dim3(1024), 0, stream,
                       x, W_in, b_in, W_rec, b_rec, W_cg, b_cg, W_eg, b_eg, tau, states);
    hipLaunchKernelGGL(ltc_out, dim3(BB * SS / 2), dim3(256), 0, stream,
                       states, W_out, b_out, outputs);
}

// Round 4
// 16579.794 us; speedup vs baseline: 1.6235x; 1.6235x over previous
//
#include <hip/hip_runtime.h>

#define BB 64
#define SS 1024
#define II 128
#define HH 256
#define OO 128

__device__ __forceinline__ unsigned pack_bf2(float a, float b) {
    unsigned ua = __float_as_uint(a);
    unsigned ub = __float_as_uint(b);
    ua = (ua + 0x7fffu + ((ua >> 16) & 1u)) >> 16;          // RNE bf16, low half
    ub = (ub + 0x7fffu + ((ub >> 16) & 1u)) & 0xffff0000u;  // RNE bf16, high half
    return ua | ub;
}
__device__ __forceinline__ float blo(unsigned u) { return __uint_as_float(u << 16); }
__device__ __forceinline__ float bhi(unsigned u) { return __uint_as_float(u & 0xffff0000u); }

// ---------------------------------------------------------------------------
// Kernel A: inp[b,t,h] = x[b,t,:] @ W_in[h,:] + b_in[h]  -> states region
// Block = 256 thr, tile = 64 rows. Lane = row (x in regs), W_in rows broadcast.
// LDS transpose for coalesced stores.
// ---------------------------------------------------------------------------
__global__ __launch_bounds__(256)
void ltc_inproj(const float* __restrict__ x, const float* __restrict__ W_in,
                const float* __restrict__ b_in, float* __restrict__ inp)
{
    __shared__ float smem[64 * 130];            // 33.3 KB; xs then reused as os
    const int t = threadIdx.x;
    const int l = t & 63, w = t >> 6;
    const int r0 = blockIdx.x * 64;

    // stage x tile [64][128] coalesced into padded LDS
    float2* xs2 = (float2*)smem;                // [64][65] float2 (row stride 130 dw)
    for (int idx = t; idx < 64 * 64; idx += 256) {
        int row = idx >> 6, c2 = idx & 63;
        xs2[row * 65 + c2] = ((const float2*)x)[(size_t)(r0 + row) * 64 + c2];
    }
    __syncthreads();
    float xr[128];
#pragma unroll
    for (int i = 0; i < 64; ++i) {
        float2 v = xs2[l * 65 + i];
        xr[2 * i] = v.x; xr[2 * i + 1] = v.y;
    }
    __syncthreads();                             // xs dead; smem becomes os[64][128]

    for (int ph = 0; ph < 2; ++ph) {
        for (int i = 0; i < 32; ++i) {
            const int hh = 128 * ph + 32 * w + i;        // phase covers contiguous [128ph,128ph+128)
            const float4* wr = (const float4*)(W_in + (size_t)hh * II);
            float a0 = b_in[hh], a1 = 0.f, a2 = 0.f, a3 = 0.f;
#pragma unroll
            for (int j = 0; j < 32; ++j) {
                float4 wv = wr[j];                       // broadcast (same addr all lanes)
                a0 = fmaf(wv.x, xr[4 * j + 0], a0);
                a1 = fmaf(wv.y, xr[4 * j + 1], a1);
                a2 = fmaf(wv.z, xr[4 * j + 2], a2);
                a3 = fmaf(wv.w, xr[4 * j + 3], a3);
            }
            smem[l * 128 + ((32 * w + i + l) & 127)] = a0 + a1 + a2 + a3;  // swizzled os
        }
        __syncthreads();
        for (int k = 0; k < 32; ++k) {                   // coalesced dump
            int idx = k * 256 + t;
            int row = idx >> 7, c = idx & 127;
            inp[(size_t)(r0 + row) * HH + 128 * ph + c] = smem[row * 128 + ((c + row) & 127)];
        }
        __syncthreads();
    }
}

// ---------------------------------------------------------------------------
// Kernel B: persistent recurrence. 64 blocks x 512 thr. Register-resident bf16
// weights: thread (r, half) holds cols [half*128, half*128+128) of W_rec/W_cg/
// W_eg row r as 192 packed dwords. h stays f32 in LDS. inp prefetched from the
// states region (written by kernel A), overwritten with h after consumption.
// ---------------------------------------------------------------------------
__global__ __launch_bounds__(512, 2)
void ltc_recurrent(const float* __restrict__ W_rec, const float* __restrict__ b_rec,
                   const float* __restrict__ W_cg,  const float* __restrict__ b_cg,
                   const float* __restrict__ W_eg,  const float* __restrict__ b_eg,
                   const float* __restrict__ tau,
                   float* __restrict__ st)          // states region [B,S,H], pre-filled with inp
{
    const int b = blockIdx.x, t = threadIdx.x;
    const int r = t & 255, half = t >> 8;

    __shared__ float h_s[HH];
    __shared__ float part[2][3][HH];

    unsigned wreg[192];
    {
        const int base = r * 128 + half * 64;    // float2 index into [256][128] float2 rows
        const float2* R2 = (const float2*)W_rec;
        const float2* C2 = (const float2*)W_cg;
        const float2* E2 = (const float2*)W_eg;
#pragma unroll
        for (int j = 0; j < 64; ++j) { float2 v = R2[base + j]; wreg[j] = pack_bf2(v.x, v.y); }
#pragma unroll
        for (int j = 0; j < 64; ++j) { float2 v = C2[base + j]; wreg[64 + j] = pack_bf2(v.x, v.y); }
#pragma unroll
        for (int j = 0; j < 64; ++j) { float2 v = E2[base + j]; wreg[128 + j] = pack_bf2(v.x, v.y); }
    }

    float brec = 0.f, bcg = 0.f, beg = 0.f, tinv = 0.f, inpC = 0.f;
    float* stb = st + (size_t)b * SS * HH;
    if (t < HH) {
        brec = b_rec[t]; bcg = b_cg[t]; beg = b_eg[t];
        tinv = 1.0f / tau[t];
        h_s[t] = 0.f;
        inpC = stb[t];                           // inp for step 0
    }
    const float4* h4 = (const float4*)h_s + half * 32;

    for (int s = 0; s < SS; ++s) {
        __syncthreads();                         // prev pointwise h_s visible; part free
        float inpN = 0.f;
        if (t < HH && s + 1 < SS) inpN = stb[(size_t)(s + 1) * HH + t];  // prefetch next inp

        float a0 = 0.f, a1 = 0.f, b0 = 0.f, b1 = 0.f, c0 = 0.f, c1 = 0.f;
#pragma unroll
        for (int i = 0; i < 32; ++i) {
            float4 hv = h4[i];                   // broadcast LDS read
            unsigned r0p = wreg[2 * i],       r1p = wreg[2 * i + 1];
            unsigned g0p = wreg[64 + 2 * i],  g1p = wreg[64 + 2 * i + 1];
            unsigned e0p = wreg[128 + 2 * i], e1p = wreg[128 + 2 * i + 1];
            a0 = fmaf(blo(r0p), hv.x, a0); a1 = fmaf(bhi(r0p), hv.y, a1);
            b0 = fmaf(blo(g0p), hv.x, b0); b1 = fmaf(bhi(g0p), hv.y, b1);
            c0 = fmaf(blo(e0p), hv.x, c0); c1 = fmaf(bhi(e0p), hv.y, c1);
            a0 = fmaf(blo(r1p), hv.z, a0); a1 = fmaf(bhi(r1p), hv.w, a1);
            b0 = fmaf(blo(g1p), hv.z, b0); b1 = fmaf(bhi(g1p), hv.w, b1);
            c0 = fmaf(blo(e1p), hv.z, c0); c1 = fmaf(bhi(e1p), hv.w, c1);
        }
        part[half][0][r] = a0 + a1;
        part[half][1][r] = b0 + b1;
        part[half][2][r] = c0 + c1;
        __syncthreads();                         // all partials ready; dots done -> h_s writable

        if (t < HH) {
            float rec = part[0][0][t] + part[1][0][t] + brec;
            float cgp = part[0][1][t] + part[1][1][t] + bcg;
            float egp = part[0][2][t] + part[1][2][t] + beg;
            float h   = h_s[t];
            float cm  = 1.0f / (1.0f + expf(-cgp));
            float em  = tanhf(egp);
            float pre = inpC + rec;
            float rl  = pre > 0.f ? pre : 0.f;
            float dh  = (rl - h) * tinv * cm + 0.1f * em;
            float hn  = fmaf(0.1f, dh, h);
            h_s[t] = hn;
            stb[(size_t)s * HH + t] = hn;        // overwrite consumed inp slot with state
        }
        inpC = inpN;
    }
}

// ---------------------------------------------------------------------------
// Kernel C: outputs[row,o] = b_out[o] + states[row,:] @ W_out[o,:]
// Same pattern as A: lane = row (states row in 256 regs), W_out broadcast,
// LDS-transposed coalesced stores. K = 256 staged in 2 phases.
// ---------------------------------------------------------------------------
__global__ __launch_bounds__(256, 1)
void ltc_out(const float* __restrict__ states, const float* __restrict__ W_out,
             const float* __restrict__ b_out, float* __restrict__ outputs)
{
    __shared__ float smem[64 * 130];
    const int t = threadIdx.x;
    const int l = t & 63, w = t >> 6;
    const int r0 = blockIdx.x * 64;

    float sr[256];
    float2* xs2 = (float2*)smem;
    for (int ph = 0; ph < 2; ++ph) {            // stage k in halves of 128
        for (int idx = t; idx < 64 * 64; idx += 256) {
            int row = idx >> 6, c2 = idx & 63;
            xs2[row * 65 + c2] = ((const float2*)states)[(size_t)(r0 + row) * 128 + 64 * ph + c2];
        }
        __syncthreads();
#pragma unroll
        for (int i = 0; i < 64; ++i) {
            float2 v = xs2[l * 65 + i];
            sr[128 * ph + 2 * i] = v.x; sr[128 * ph + 2 * i + 1] = v.y;
        }
        __syncthreads();
    }

    {
        for (int i = 0; i < 32; ++i) {
            const int oo = 32 * w + i;
            const float4* wr = (const float4*)(W_out + (size_t)oo * HH);
            float a0 = b_out[oo], a1 = 0.f, a2 = 0.f, a3 = 0.f;
#pragma unroll
            for (int j = 0; j < 64; ++j) {
                float4 wv = wr[j];
                a0 = fmaf(wv.x, sr[4 * j + 0], a0);
                a1 = fmaf(wv.y, sr[4 * j + 1], a1);
                a2 = fmaf(wv.z, sr[4 * j + 2], a2);
                a3 = fmaf(wv.w, sr[4 * j + 3], a3);
            }
            smem[l * 128 + ((oo + l) & 127)] = a0 + a1 + a2 + a3;
        }
        __syncthreads();
        for (int k = 0; k < 32; ++k) {
            int idx = k * 256 + t;
            int row = idx >> 7, c = idx & 127;
            outputs[(size_t)(r0 + row) * OO + c] = smem[row * 128 + ((c + row) & 127)];
        }
    }
}

extern "C" void kernel_launch(void* const* d_in, const int* in_sizes, int n_in,
                              void* d_out, int out_size, void* d_ws, size_t ws_size,
                              hipStream_t stream) {
    const float* x      = (const float*)d_in[0];
    const float* W_in   = (const float*)d_in[1];
    const float* b_in   = (const float*)d_in[2];
    const float* W_rec  = (const float*)d_in[3];
    const float* b_rec  = (const float*)d_in[4];
    const float* W_out  = (const float*)d_in[5];
    const float* b_out  = (const float*)d_in[6];
    const float* W_cg   = (const float*)d_in[7];
    const float* b_cg   = (const float*)d_in[8];
    const float* W_eg   = (const float*)d_in[9];
    const float* b_eg   = (const float*)d_in[10];
    const float* tau    = (const float*)d_in[11];

    float* outputs = (float*)d_out;                       // [B,S,O]
    float* states  = outputs + (size_t)BB * SS * OO;      // [B,S,H] (inp staging, then h)

    hipLaunchKernelGGL(ltc_inproj, dim3(BB * SS / 64), dim3(256), 0, stream,
                       x, W_in, b_in, states);
    hipLaunchKernelGGL(ltc_recurrent, dim3(BB), dim3(512), 0, stream,
                       W_rec, b_rec, W_cg, b_cg, W_eg, b_eg, tau, states);
    hipLaunchKernelGGL(ltc_out, dim3(BB * SS / 64), dim3(256), 0, stream,
                       states, W_out, b_out, outputs);
}

// Round 5
// 4290.519 us; speedup vs baseline: 6.2736x; 3.8643x over previous
//
#include <hip/hip_runtime.h>

#define BB 64
#define SS 1024
#define II 128
#define HH 256
#define OO 128

#if __has_builtin(__builtin_amdgcn_fdot2)
#define HAVE_DOT2 1
#endif

typedef __fp16 h2_t __attribute__((ext_vector_type(2)));

__device__ __forceinline__ float blo(unsigned u) { return __uint_as_float(u << 16); }
__device__ __forceinline__ float bhi(unsigned u) { return __uint_as_float(u & 0xffff0000u); }

__device__ __forceinline__ unsigned pack_bf2(float a, float b) {
    unsigned ua = __float_as_uint(a);
    unsigned ub = __float_as_uint(b);
    ua = (ua + 0x7fffu + ((ua >> 16) & 1u)) >> 16;          // RNE bf16 -> low half
    ub = (ub + 0x7fffu + ((ub >> 16) & 1u)) & 0xffff0000u;  // RNE bf16 -> high half
    return ua | ub;
}

// pack 2 f32 -> one dword of 2x16-bit (f16 if dot2 available, else bf16)
__device__ __forceinline__ unsigned packh(float a, float b) {
#ifdef HAVE_DOT2
    union { h2_t h; unsigned u; } cv;
    cv.h = __builtin_amdgcn_cvt_pkrtz(a, b);   // v_cvt_pkrtz_f16_f32, 1 inst
    return cv.u;
#else
    return pack_bf2(a, b);
#endif
}

// acc += w.lo*h.lo + w.hi*h.hi  (1 inst on dot2 path)
__device__ __forceinline__ float dot2acc(unsigned w, unsigned h, float acc) {
#ifdef HAVE_DOT2
    union { unsigned u; h2_t h; } cw, ch;
    cw.u = w; ch.u = h;
    return __builtin_amdgcn_fdot2(cw.h, ch.h, acc, false);
#else
    return fmaf(blo(w), blo(h), fmaf(bhi(w), bhi(h), acc));
#endif
}

// ---------------------------------------------------------------------------
// Kernel A: inp[b,t,h] = x[b,t,:] @ W_in[h,:] + b_in[h]  -> states region
// (unchanged from round 4 — passed; revisit if it shows up in top-5)
// ---------------------------------------------------------------------------
__global__ __launch_bounds__(256)
void ltc_inproj(const float* __restrict__ x, const float* __restrict__ W_in,
                const float* __restrict__ b_in, float* __restrict__ inp)
{
    __shared__ float smem[64 * 130];
    const int t = threadIdx.x;
    const int l = t & 63, w = t >> 6;
    const int r0 = blockIdx.x * 64;

    float2* xs2 = (float2*)smem;                // [64][65] float2
    for (int idx = t; idx < 64 * 64; idx += 256) {
        int row = idx >> 6, c2 = idx & 63;
        xs2[row * 65 + c2] = ((const float2*)x)[(size_t)(r0 + row) * 64 + c2];
    }
    __syncthreads();
    float xr[128];
#pragma unroll
    for (int i = 0; i < 64; ++i) {
        float2 v = xs2[l * 65 + i];
        xr[2 * i] = v.x; xr[2 * i + 1] = v.y;
    }
    __syncthreads();

    for (int ph = 0; ph < 2; ++ph) {
        for (int i = 0; i < 32; ++i) {
            const int hh = 128 * ph + 32 * w + i;
            const float4* wr = (const float4*)(W_in + (size_t)hh * II);
            float a0 = b_in[hh], a1 = 0.f, a2 = 0.f, a3 = 0.f;
#pragma unroll
            for (int j = 0; j < 32; ++j) {
                float4 wv = wr[j];
                a0 = fmaf(wv.x, xr[4 * j + 0], a0);
                a1 = fmaf(wv.y, xr[4 * j + 1], a1);
                a2 = fmaf(wv.z, xr[4 * j + 2], a2);
                a3 = fmaf(wv.w, xr[4 * j + 3], a3);
            }
            smem[l * 128 + ((32 * w + i + l) & 127)] = a0 + a1 + a2 + a3;
        }
        __syncthreads();
        for (int k = 0; k < 32; ++k) {
            int idx = k * 256 + t;
            int row = idx >> 7, c = idx & 127;
            inp[(size_t)(r0 + row) * HH + 128 * ph + c] = smem[row * 128 + ((c + row) & 127)];
        }
        __syncthreads();
    }
}

// ---------------------------------------------------------------------------
// Kernel B: persistent recurrence. 64 blocks x 256 thr, launch_bounds(256,1)
// => VGPR cap 512 (no-spill regime <=450). Thread t holds FULL row t of
// W_rec/W_cg/W_eg as 3x128 packed-f16 dwords (384 VGPRs). h broadcast from
// LDS as packed f16 pairs; pointwise threads (t<128) keep h in f32 regs.
// ---------------------------------------------------------------------------
__global__ __launch_bounds__(256, 1)
void ltc_recurrent(const float* __restrict__ W_rec, const float* __restrict__ b_rec,
                   const float* __restrict__ W_cg,  const float* __restrict__ b_cg,
                   const float* __restrict__ W_eg,  const float* __restrict__ b_eg,
                   const float* __restrict__ tau,
                   float* __restrict__ st)          // [B,S,H]: pre-filled with inp, becomes states
{
    const int b = blockIdx.x, t = threadIdx.x;

    __shared__ __align__(16) unsigned h_p[HH / 2];   // h as 128 packed f16 pairs
    __shared__ __align__(16) float part[3][HH];

    // ---- register-resident packed weights: rows t of R/C/E --------------
    unsigned wR[128], wC[128], wE[128];
    {
        const float2* R2 = (const float2*)W_rec + (size_t)t * 128;
        const float2* C2 = (const float2*)W_cg  + (size_t)t * 128;
        const float2* E2 = (const float2*)W_eg  + (size_t)t * 128;
#pragma unroll
        for (int j = 0; j < 128; ++j) {
            float2 v = R2[j]; wR[j] = packh(v.x, v.y);
            if ((j & 7) == 7) __builtin_amdgcn_sched_barrier(0);  // cap load-batch pressure
        }
#pragma unroll
        for (int j = 0; j < 128; ++j) {
            float2 v = C2[j]; wC[j] = packh(v.x, v.y);
            if ((j & 7) == 7) __builtin_amdgcn_sched_barrier(0);
        }
#pragma unroll
        for (int j = 0; j < 128; ++j) {
            float2 v = E2[j]; wE[j] = packh(v.x, v.y);
            if ((j & 7) == 7) __builtin_amdgcn_sched_barrier(0);
        }
    }
    const float bR = b_rec[t], bC = b_cg[t], bE = b_eg[t];

    float* stb = st + (size_t)b * SS * HH;
    float2* stb2 = (float2*)stb;

    float ti0 = 0.f, ti1 = 0.f, h0r = 0.f, h1r = 0.f;
    float2 inpC = {0.f, 0.f};
    if (t < 128) {
        float2 tv = ((const float2*)tau)[t];
        ti0 = 1.0f / tv.x; ti1 = 1.0f / tv.y;
        inpC = stb2[t];        // inp for step 0, rows 2t,2t+1
        h_p[t] = 0u;           // h0 = 0
    }
    __syncthreads();

    const uint4* hp4 = (const uint4*)h_p;

    for (int s = 0; s < SS; ++s) {
        float2 inpN = {0.f, 0.f};
        if (t < 128 && s + 1 < SS) inpN = stb2[(size_t)(s + 1) * 128 + t];  // prefetch

        float aR0 = bR, aR1 = 0.f, aC0 = bC, aC1 = 0.f, aE0 = bE, aE1 = 0.f;
#pragma unroll
        for (int c = 0; c < 8; ++c) {                   // 8 chunks x 16 packed h dwords
            uint4 q0 = hp4[c * 4 + 0], q1 = hp4[c * 4 + 1];
            uint4 q2 = hp4[c * 4 + 2], q3 = hp4[c * 4 + 3];   // broadcast ds_read_b128
            unsigned hw[16] = {q0.x, q0.y, q0.z, q0.w, q1.x, q1.y, q1.z, q1.w,
                               q2.x, q2.y, q2.z, q2.w, q3.x, q3.y, q3.z, q3.w};
#pragma unroll
            for (int j = 0; j < 16; j += 2) {
                aR0 = dot2acc(wR[c * 16 + j],     hw[j],     aR0);
                aC0 = dot2acc(wC[c * 16 + j],     hw[j],     aC0);
                aE0 = dot2acc(wE[c * 16 + j],     hw[j],     aE0);
                aR1 = dot2acc(wR[c * 16 + j + 1], hw[j + 1], aR1);
                aC1 = dot2acc(wC[c * 16 + j + 1], hw[j + 1], aC1);
                aE1 = dot2acc(wE[c * 16 + j + 1], hw[j + 1], aE1);
            }
        }
        part[0][t] = aR0 + aR1;
        part[1][t] = aC0 + aC1;
        part[2][t] = aE0 + aE1;
        __syncthreads();                                 // partials ready; h_p reads done

        if (t < 128) {                                   // pointwise: rows 2t, 2t+1
            float2 rc = ((const float2*)part[0])[t];
            float2 cg = ((const float2*)part[1])[t];
            float2 eg = ((const float2*)part[2])[t];
            float cm0 = 1.0f / (1.0f + expf(-cg.x));
            float cm1 = 1.0f / (1.0f + expf(-cg.y));
            float em0 = tanhf(eg.x), em1 = tanhf(eg.y);
            float p0 = inpC.x + rc.x, p1 = inpC.y + rc.y;
            float rl0 = p0 > 0.f ? p0 : 0.f;
            float rl1 = p1 > 0.f ? p1 : 0.f;
            float dh0 = (rl0 - h0r) * ti0 * cm0 + 0.1f * em0;
            float dh1 = (rl1 - h1r) * ti1 * cm1 + 0.1f * em1;
            h0r = fmaf(0.1f, dh0, h0r);                  // h stays full f32 across steps
            h1r = fmaf(0.1f, dh1, h1r);
            h_p[t] = packh(h0r, h1r);                    // rounded copy only feeds the dots
            float2 hv; hv.x = h0r; hv.y = h1r;
            stb2[(size_t)s * 128 + t] = hv;              // overwrite consumed inp slot
        }
        inpC = inpN;
        __syncthreads();                                 // h_p ready for next step's dots
    }
}

// ---------------------------------------------------------------------------
// Kernel C: outputs[row,o] = b_out[o] + states[row,:] @ W_out[o,:]
// (unchanged from round 4)
// ---------------------------------------------------------------------------
__global__ __launch_bounds__(256, 1)
void ltc_out(const float* __restrict__ states, const float* __restrict__ W_out,
             const float* __restrict__ b_out, float* __restrict__ outputs)
{
    __shared__ float smem[64 * 130];
    const int t = threadIdx.x;
    const int l = t & 63, w = t >> 6;
    const int r0 = blockIdx.x * 64;

    float sr[256];
    float2* xs2 = (float2*)smem;
    for (int ph = 0; ph < 2; ++ph) {
        for (int idx = t; idx < 64 * 64; idx += 256) {
            int row = idx >> 6, c2 = idx & 63;
            xs2[row * 65 + c2] = ((const float2*)states)[(size_t)(r0 + row) * 128 + 64 * ph + c2];
        }
        __syncthreads();
#pragma unroll
        for (int i = 0; i < 64; ++i) {
            float2 v = xs2[l * 65 + i];
            sr[128 * ph + 2 * i] = v.x; sr[128 * ph + 2 * i + 1] = v.y;
        }
        __syncthreads();
    }

    for (int i = 0; i < 32; ++i) {
        const int oo = 32 * w + i;
        const float4* wr = (const float4*)(W_out + (size_t)oo * HH);
        float a0 = b_out[oo], a1 = 0.f, a2 = 0.f, a3 = 0.f;
#pragma unroll
        for (int j = 0; j < 64; ++j) {
            float4 wv = wr[j];
            a0 = fmaf(wv.x, sr[4 * j + 0], a0);
            a1 = fmaf(wv.y, sr[4 * j + 1], a1);
            a2 = fmaf(wv.z, sr[4 * j + 2], a2);
            a3 = fmaf(wv.w, sr[4 * j + 3], a3);
        }
        smem[l * 128 + ((oo + l) & 127)] = a0 + a1 + a2 + a3;
    }
    __syncthreads();
    for (int k = 0; k < 32; ++k) {
        int idx = k * 256 + t;
        int row = idx >> 7, c = idx & 127;
        outputs[(size_t)(r0 + row) * OO + c] = smem[row * 128 + ((c + row) & 127)];
    }
}

extern "C" void kernel_launch(void* const* d_in, const int* in_sizes, int n_in,
                              void* d_out, int out_size, void* d_ws, size_t ws_size,
                              hipStream_t stream) {
    const float* x      = (const float*)d_in[0];
    const float* W_in   = (const float*)d_in[1];
    const float* b_in   = (const float*)d_in[2];
    const float* W_rec  = (const float*)d_in[3];
    const float* b_rec  = (const float*)d_in[4];
    const float* W_out  = (const float*)d_in[5];
    const float* b_out  = (const float*)d_in[6];
    const float* W_cg   = (const float*)d_in[7];
    const float* b_cg   = (const float*)d_in[8];
    const float* W_eg   = (const float*)d_in[9];
    const float* b_eg   = (const float*)d_in[10];
    const float* tau    = (const float*)d_in[11];

    float* outputs = (float*)d_out;                       // [B,S,O]
    float* states  = outputs + (size_t)BB * SS * OO;      // [B,S,H] (inp staging -> states)

    hipLaunchKernelGGL(ltc_inproj, dim3(BB * SS / 64), dim3(256), 0, stream,
                       x, W_in, b_in, states);
    hipLaunchKernelGGL(ltc_recurrent, dim3(BB), dim3(256), 0, stream,
                       W_rec, b_rec, W_cg, b_cg, W_eg, b_eg, tau, states);
    hipLaunchKernelGGL(ltc_out, dim3(BB * SS / 64), dim3(256), 0, stream,
                       states, W_out, b_out, outputs);
}

// Round 6
// 2514.728 us; speedup vs baseline: 10.7037x; 1.7062x over previous
//
#include <hip/hip_runtime.h>

#define BB 64
#define SS 1024
#define II 128
#define HH 256
#define OO 128

#if __has_builtin(__builtin_amdgcn_fdot2)
#define HAVE_DOT2 1
#endif

typedef __fp16 h2_t __attribute__((ext_vector_type(2)));

__device__ __forceinline__ float blo(unsigned u) { return __uint_as_float(u << 16); }
__device__ __forceinline__ float bhi(unsigned u) { return __uint_as_float(u & 0xffff0000u); }

__device__ __forceinline__ unsigned pack_bf2(float a, float b) {
    unsigned ua = __float_as_uint(a);
    unsigned ub = __float_as_uint(b);
    ua = (ua + 0x7fffu + ((ua >> 16) & 1u)) >> 16;
    ub = (ub + 0x7fffu + ((ub >> 16) & 1u)) & 0xffff0000u;
    return ua | ub;
}

__device__ __forceinline__ unsigned packh(float a, float b) {
#ifdef HAVE_DOT2
    union { h2_t h; unsigned u; } cv;
    cv.h = __builtin_amdgcn_cvt_pkrtz(a, b);   // v_cvt_pkrtz_f16_f32
    return cv.u;
#else
    return pack_bf2(a, b);
#endif
}

__device__ __forceinline__ float dot2acc(unsigned w, unsigned h, float acc) {
#ifdef HAVE_DOT2
    union { unsigned u; h2_t h; } cw, ch;
    cw.u = w; ch.u = h;
    return __builtin_amdgcn_fdot2(cw.h, ch.h, acc, false);
#else
    return fmaf(blo(w), blo(h), fmaf(bhi(w), bhi(h), acc));
#endif
}

// ---------------------------------------------------------------------------
// Kernel A: inp[b,t,h] = x[b,t,:] @ W_in[h,:] + b_in[h]  -> states region
// ---------------------------------------------------------------------------
__global__ __launch_bounds__(256)
void ltc_inproj(const float* __restrict__ x, const float* __restrict__ W_in,
                const float* __restrict__ b_in, float* __restrict__ inp)
{
    __shared__ float smem[64 * 130];
    const int t = threadIdx.x;
    const int l = t & 63, w = t >> 6;
    const int r0 = blockIdx.x * 64;

    float2* xs2 = (float2*)smem;                // [64][65] float2
    for (int idx = t; idx < 64 * 64; idx += 256) {
        int row = idx >> 6, c2 = idx & 63;
        xs2[row * 65 + c2] = ((const float2*)x)[(size_t)(r0 + row) * 64 + c2];
    }
    __syncthreads();
    float xr[128];
#pragma unroll
    for (int i = 0; i < 64; ++i) {
        float2 v = xs2[l * 65 + i];
        xr[2 * i] = v.x; xr[2 * i + 1] = v.y;
    }
    __syncthreads();

    for (int ph = 0; ph < 2; ++ph) {
        for (int i = 0; i < 32; ++i) {
            const int hh = 128 * ph + 32 * w + i;
            const float4* wr = (const float4*)(W_in + (size_t)hh * II);
            float a0 = b_in[hh], a1 = 0.f, a2 = 0.f, a3 = 0.f;
#pragma unroll
            for (int j = 0; j < 32; ++j) {
                float4 wv = wr[j];
                a0 = fmaf(wv.x, xr[4 * j + 0], a0);
                a1 = fmaf(wv.y, xr[4 * j + 1], a1);
                a2 = fmaf(wv.z, xr[4 * j + 2], a2);
                a3 = fmaf(wv.w, xr[4 * j + 3], a3);
            }
            smem[l * 128 + ((32 * w + i + l) & 127)] = a0 + a1 + a2 + a3;
        }
        __syncthreads();
        for (int k = 0; k < 32; ++k) {
            int idx = k * 256 + t;
            int row = idx >> 7, c = idx & 127;
            inp[(size_t)(r0 + row) * HH + 128 * ph + c] = smem[row * 128 + ((c + row) & 127)];
        }
        __syncthreads();
    }
}

// ---------------------------------------------------------------------------
// Kernel B: persistent recurrence. 64 blocks x 512 thr (2 waves/SIMD).
// Thread (r, half) holds cols [half*128, half*128+128) of rows r of
// W_rec/W_cg/W_eg as 3 x 64 packed-f16 dwords = 192 VGPRs (+~40 temps < 256
// arch-VGPR limit; split arrays so SROA promotes them — round-5 lesson).
// Biases applied in the pointwise phase. h stays f32 in pointwise registers;
// only the packed copy feeding the dots is rounded.
// ---------------------------------------------------------------------------
__global__ __launch_bounds__(512)
void ltc_recurrent(const float* __restrict__ W_rec, const float* __restrict__ b_rec,
                   const float* __restrict__ W_cg,  const float* __restrict__ b_cg,
                   const float* __restrict__ W_eg,  const float* __restrict__ b_eg,
                   const float* __restrict__ tau,
                   float* __restrict__ st)          // [B,S,H]: inp staged in, states out
{
    const int b = blockIdx.x, t = threadIdx.x;
    const int r = t & 255, half = t >> 8;

    __shared__ __align__(16) unsigned h_p[HH / 2];   // h as 128 packed f16 pairs
    __shared__ __align__(16) float part[2][3][HH];   // [half][gate][row]

    unsigned wR[64], wC[64], wE[64];
    {
        const float4* R4 = (const float4*)(W_rec + (size_t)r * HH + half * 128);
        const float4* C4 = (const float4*)(W_cg  + (size_t)r * HH + half * 128);
        const float4* E4 = (const float4*)(W_eg  + (size_t)r * HH + half * 128);
#pragma unroll
        for (int j = 0; j < 32; ++j) {
            float4 v = R4[j]; wR[2 * j] = packh(v.x, v.y); wR[2 * j + 1] = packh(v.z, v.w);
        }
#pragma unroll
        for (int j = 0; j < 32; ++j) {
            float4 v = C4[j]; wC[2 * j] = packh(v.x, v.y); wC[2 * j + 1] = packh(v.z, v.w);
        }
#pragma unroll
        for (int j = 0; j < 32; ++j) {
            float4 v = E4[j]; wE[2 * j] = packh(v.x, v.y); wE[2 * j + 1] = packh(v.z, v.w);
        }
    }

    float* stb = st + (size_t)b * SS * HH;
    float2* stb2 = (float2*)stb;

    // pointwise state (threads t < 128 own rows 2t, 2t+1)
    float ti0 = 0.f, ti1 = 0.f, h0r = 0.f, h1r = 0.f;
    float2 bR2 = {0.f, 0.f}, bC2 = {0.f, 0.f}, bE2 = {0.f, 0.f};
    float2 inpC = {0.f, 0.f};
    if (t < 128) {
        float2 tv = ((const float2*)tau)[t];
        ti0 = 1.0f / tv.x; ti1 = 1.0f / tv.y;
        bR2 = ((const float2*)b_rec)[t];
        bC2 = ((const float2*)b_cg)[t];
        bE2 = ((const float2*)b_eg)[t];
        inpC = stb2[t];
        h_p[t] = 0u;
    }
    __syncthreads();

    const uint4* hp4 = (const uint4*)h_p + half * 16;  // this half's 16 uint4

    for (int s = 0; s < SS; ++s) {
        float2 inpN = {0.f, 0.f};
        if (t < 128 && s + 1 < SS) inpN = stb2[(size_t)(s + 1) * 128 + t];

        float aR0 = 0.f, aR1 = 0.f, aC0 = 0.f, aC1 = 0.f, aE0 = 0.f, aE1 = 0.f;
#pragma unroll
        for (int c = 0; c < 4; ++c) {                   // 4 chunks x 16 packed dwords
            uint4 q0 = hp4[c * 4 + 0], q1 = hp4[c * 4 + 1];
            uint4 q2 = hp4[c * 4 + 2], q3 = hp4[c * 4 + 3];
            unsigned hw[16] = {q0.x, q0.y, q0.z, q0.w, q1.x, q1.y, q1.z, q1.w,
                               q2.x, q2.y, q2.z, q2.w, q3.x, q3.y, q3.z, q3.w};
#pragma unroll
            for (int j = 0; j < 16; j += 2) {
                aR0 = dot2acc(wR[c * 16 + j],     hw[j],     aR0);
                aC0 = dot2acc(wC[c * 16 + j],     hw[j],     aC0);
                aE0 = dot2acc(wE[c * 16 + j],     hw[j],     aE0);
                aR1 = dot2acc(wR[c * 16 + j + 1], hw[j + 1], aR1);
                aC1 = dot2acc(wC[c * 16 + j + 1], hw[j + 1], aC1);
                aE1 = dot2acc(wE[c * 16 + j + 1], hw[j + 1], aE1);
            }
        }
        part[half][0][r] = aR0 + aR1;
        part[half][1][r] = aC0 + aC1;
        part[half][2][r] = aE0 + aE1;
        __syncthreads();                                 // partials ready; h_p reads done

        if (t < 128) {                                   // rows 2t, 2t+1
            float2 rA = ((const float2*)part[0][0])[t], rB = ((const float2*)part[1][0])[t];
            float2 cA = ((const float2*)part[0][1])[t], cB = ((const float2*)part[1][1])[t];
            float2 eA = ((const float2*)part[0][2])[t], eB = ((const float2*)part[1][2])[t];
            float rec0 = rA.x + rB.x + bR2.x, rec1 = rA.y + rB.y + bR2.y;
            float cg0  = cA.x + cB.x + bC2.x, cg1  = cA.y + cB.y + bC2.y;
            float eg0  = eA.x + eB.x + bE2.x, eg1  = eA.y + eB.y + bE2.y;
            float cm0 = 1.0f / (1.0f + expf(-cg0));
            float cm1 = 1.0f / (1.0f + expf(-cg1));
            float em0 = tanhf(eg0), em1 = tanhf(eg1);
            float p0 = inpC.x + rec0, p1 = inpC.y + rec1;
            float rl0 = p0 > 0.f ? p0 : 0.f;
            float rl1 = p1 > 0.f ? p1 : 0.f;
            float dh0 = (rl0 - h0r) * ti0 * cm0 + 0.1f * em0;
            float dh1 = (rl1 - h1r) * ti1 * cm1 + 0.1f * em1;
            h0r = fmaf(0.1f, dh0, h0r);
            h1r = fmaf(0.1f, dh1, h1r);
            h_p[t] = packh(h0r, h1r);
            float2 hv; hv.x = h0r; hv.y = h1r;
            stb2[(size_t)s * 128 + t] = hv;
        }
        inpC = inpN;
        __syncthreads();                                 // h_p visible for next step
    }
}

// ---------------------------------------------------------------------------
// Kernel C: outputs[row,o] = b_out[o] + states[row,:] @ W_out[o,:]
// Two K-phases of 128 with 32 per-thread accumulators (no 256-dword array,
// no spill). Lane = row, W_out rows broadcast, LDS-swizzled coalesced store.
// ---------------------------------------------------------------------------
__global__ __launch_bounds__(256)
void ltc_out(const float* __restrict__ states, const float* __restrict__ W_out,
             const float* __restrict__ b_out, float* __restrict__ outputs)
{
    __shared__ float smem[64 * 130];
    const int t = threadIdx.x;
    const int l = t & 63, w = t >> 6;
    const int r0 = blockIdx.x * 64;

    float osacc[32];
#pragma unroll
    for (int i = 0; i < 32; ++i) osacc[i] = b_out[32 * w + i];

    float2* xs2 = (float2*)smem;                // [64][65] float2
    for (int ph = 0; ph < 2; ++ph) {
        for (int idx = t; idx < 64 * 64; idx += 256) {
            int row = idx >> 6, c2 = idx & 63;
            xs2[row * 65 + c2] = ((const float2*)states)[(size_t)(r0 + row) * 128 + ph * 64 + c2];
        }
        __syncthreads();
        float xr[128];
#pragma unroll
        for (int i = 0; i < 64; ++i) {
            float2 v = xs2[l * 65 + i];
            xr[2 * i] = v.x; xr[2 * i + 1] = v.y;
        }
        __syncthreads();                        // xs consumed; safe to restage next ph

        for (int i = 0; i < 32; ++i) {
            const int oo = 32 * w + i;
            const float4* wr = (const float4*)(W_out + (size_t)oo * HH + ph * 128);
            float a0 = 0.f, a1 = 0.f, a2 = 0.f, a3 = 0.f;
#pragma unroll
            for (int j = 0; j < 32; ++j) {
                float4 wv = wr[j];
                a0 = fmaf(wv.x, xr[4 * j + 0], a0);
                a1 = fmaf(wv.y, xr[4 * j + 1], a1);
                a2 = fmaf(wv.z, xr[4 * j + 2], a2);
                a3 = fmaf(wv.w, xr[4 * j + 3], a3);
            }
            osacc[i] += (a0 + a1) + (a2 + a3);
        }
    }

    __syncthreads();                            // smem free for output staging
#pragma unroll
    for (int i = 0; i < 32; ++i)
        smem[l * 128 + ((32 * w + i + l) & 127)] = osacc[i];
    __syncthreads();
    for (int k = 0; k < 32; ++k) {
        int idx = k * 256 + t;
        int row = idx >> 7, c = idx & 127;
        outputs[(size_t)(r0 + row) * OO + c] = smem[row * 128 + ((c + row) & 127)];
    }
}

extern "C" void kernel_launch(void* const* d_in, const int* in_sizes, int n_in,
                              void* d_out, int out_size, void* d_ws, size_t ws_size,
                              hipStream_t stream) {
    const float* x      = (const float*)d_in[0];
    const float* W_in   = (const float*)d_in[1];
    const float* b_in   = (const float*)d_in[2];
    const float* W_rec  = (const float*)d_in[3];
    const float* b_rec  = (const float*)d_in[4];
    const float* W_out  = (const float*)d_in[5];
    const float* b_out  = (const float*)d_in[6];
    const float* W_cg   = (const float*)d_in[7];
    const float* b_cg   = (const float*)d_in[8];
    const float* W_eg   = (const float*)d_in[9];
    const float* b_eg   = (const float*)d_in[10];
    const float* tau    = (const float*)d_in[11];

    float* outputs = (float*)d_out;                       // [B,S,O]
    float* states  = outputs + (size_t)BB * SS * OO;      // [B,S,H] (inp staging -> states)

    hipLaunchKernelGGL(ltc_inproj, dim3(BB * SS / 64), dim3(256), 0, stream,
                       x, W_in, b_in, states);
    hipLaunchKernelGGL(ltc_recurrent, dim3(BB), dim3(512), 0, stream,
                       W_rec, b_rec, W_cg, b_cg, W_eg, b_eg, tau, states);
    hipLaunchKernelGGL(ltc_out, dim3(BB * SS / 64), dim3(256), 0, stream,
                       states, W_out, b_out, outputs);
}